// Round 5
// baseline (365.059 us; speedup 1.0000x reference)
//
#include <hip/hip_runtime.h>

// Problem shapes (fixed by setup_inputs)
namespace {
constexpr int B   = 8;
constexpr int N   = 100;
constexpr int C   = 256;
constexpr int H   = 160;
constexpr int W   = 160;
constexpr int NC  = 80;     // NUM_CLASSES
constexpr int T   = 512;    // 8 waves/block -> 2 blocks/CU
constexpr int NWV = 8;      // waves/block
constexpr int CHR = 4;      // rows per chunk
constexpr int NCH = H / CHR;// 40 chunks
}

// image_h / image_w arrive as 1-element arrays of unknown dtype (python
// scalar). Read as int32; if implausible, reinterpret the bits as float32.
__device__ inline float read_dim(const int* p) {
    int i = *p;
    if (i >= 1 && i <= (1 << 26)) return (float)i;
    return __int_as_float(i);
}

extern "C" __global__ void __launch_bounds__(T, 4)
vpe_kernel(const float* __restrict__ features,  // [B,C,H,W]
           const float* __restrict__ boxes,     // [B,N,4]
           const int*   __restrict__ gt,        // [B,N]
           const int*   __restrict__ neg_y,     // [B,NC]
           const int*   __restrict__ neg_x,     // [B,NC]
           const int*   __restrict__ imh_p,     // scalar
           const int*   __restrict__ imw_p,     // scalar
           float*       __restrict__ out)       // [B,NC,C]
{
    // One block per (b,c) plane. Build 4-row chunk column sums (26 KB, not a
    // 105 KB SAT), exclusive-scan per column, then one wave per box does
    // per-lane x-segment sums (prefix-diff + <=6 ragged global rows) and a
    // butterfly reduce. No hot-loop atomics, no shuffle scans, small LDS.
    __shared__ float pre[(NCH + 1) * W];   // chunk sums -> exclusive prefixes (26.2 KB)
    __shared__ float cls_sum[NC];
    __shared__ int   cls_cnt[NC];
    __shared__ int   bx1[N], bw[N], by1[N], by2[N], bcls[N];
    __shared__ float bwgt[N];

    const int tid  = threadIdx.x;
    const int wv   = tid >> 6, lane = tid & 63;
    const int b    = blockIdx.x / C;
    const int c    = blockIdx.x % C;
    const float* plane = features + (size_t)(b * C + c) * (H * W);

    if (tid < NC) { cls_sum[tid] = 0.f; cls_cnt[tid] = 0; }
    __syncthreads();

    // Box setup (uniform per b; recomputed per block — trivial cost).
    if (tid < N) {
        float imw = read_dim(imw_p), imh = read_dim(imh_p);
        float sx = (float)W / imw, sy = (float)H / imh;
        const float* bp = boxes + (size_t)(b * N + tid) * 4;
        int x1 = (int)fminf(fmaxf(floorf(bp[0] * sx), 0.f), (float)W);
        int y1 = (int)fminf(fmaxf(floorf(bp[1] * sy), 0.f), (float)H);
        int x2 = (int)fminf(fmaxf(floorf(bp[2] * sx), 0.f), (float)W);
        int y2 = (int)fminf(fmaxf(floorf(bp[3] * sy), 0.f), (float)H);
        bool valid = (x2 > x1) && (y2 > y1);
        bx1[tid] = x1; bw[tid] = x2 - x1; by1[tid] = y1; by2[tid] = y2;
        int cls = gt[b * N + tid];
        bcls[tid] = valid ? cls : -1;
        bwgt[tid] = 1.f / (float)max((x2 - x1) * (y2 - y1), 1);
        if (valid) atomicAdd(&cls_cnt[cls], 1);
    }

    // Phase 1: chunk column sums. 320 active threads: g = t/40 owns rows
    // [20g, 20g+20) (5 chunks), xq = t%40 owns a float4 column. All loads
    // independent & coalesced -> HBM-saturating.
    if (tid < 320) {
        const int g = tid / 40, xq = tid - g * 40;
        const float4* p4 = (const float4*)plane;   // row y: p4[y*40 + xq]
        #pragma unroll
        for (int cc = 0; cc < 5; ++cc) {
            const int ch = g * 5 + cc;
            float4 a0 = p4[(ch * CHR + 0) * 40 + xq];
            float4 a1 = p4[(ch * CHR + 1) * 40 + xq];
            float4 a2 = p4[(ch * CHR + 2) * 40 + xq];
            float4 a3 = p4[(ch * CHR + 3) * 40 + xq];
            float4 s = make_float4(a0.x + a1.x + a2.x + a3.x,
                                   a0.y + a1.y + a2.y + a3.y,
                                   a0.z + a1.z + a2.z + a3.z,
                                   a0.w + a1.w + a2.w + a3.w);
            *((float4*)&pre[ch * W + xq * 4]) = s;
        }
    }
    __syncthreads();

    // Fold class-count divisor into the per-box weight.
    if (tid < N && bcls[tid] >= 0)
        bwgt[tid] /= (float)max(cls_cnt[bcls[tid]], 1);

    // Phase 1.5: in-place exclusive prefix over the 40 chunk sums, per column
    // (one thread per column; reads independent of the running sum).
    if (tid < W) {
        float run = 0.f;
        #pragma unroll 8
        for (int ch = 0; ch < NCH; ++ch) {
            float v = pre[ch * W + tid];
            pre[ch * W + tid] = run;
            run += v;
        }
        pre[NCH * W + tid] = run;
    }
    __syncthreads();

    // Phase 2: one wave per box. Per lane: x-segment sum of (prefix diff over
    // full chunks) + ragged raw rows (global, coalesced, L2/L3-hot), then a
    // 6-step butterfly reduce; lane 0 does ONE LDS atomic per box.
    for (int n = wv; n < N; n += NWV) {
        const int cls = bcls[n];
        if (cls < 0) continue;
        const int x1 = bx1[n], w = bw[n];
        const int y1 = by1[n], y2 = by2[n];
        int chA = (y1 + CHR - 1) / CHR, chB = y2 / CHR;
        int rt0, rt1, rb0, rb1;
        bool full = chA < chB;
        if (full) { rt0 = y1; rt1 = chA * CHR; rb0 = chB * CHR; rb1 = y2; }
        else      { rt0 = y1; rt1 = y2;        rb0 = 0;         rb1 = 0;  }

        float s = 0.f;
        for (int xo = lane; xo < w; xo += 64) {
            const int x = x1 + xo;
            float t = 0.f;
            if (full) t += pre[chB * W + x] - pre[chA * W + x];
            for (int y = rt0; y < rt1; ++y) t += plane[y * W + x];
            for (int y = rb0; y < rb1; ++y) t += plane[y * W + x];
            s += t;
        }
        #pragma unroll
        for (int d = 1; d < 64; d <<= 1) s += __shfl_xor(s, d, 64);
        if (lane == 0) atomicAdd(&cls_sum[cls], s * bwgt[n]);
    }
    __syncthreads();

    // Epilogue: mean (already /cnt via bwgt) or negative-pixel fallback.
    if (tid < NC) {
        int cnt = cls_cnt[tid];
        float o = (cnt > 0) ? cls_sum[tid]
                            : plane[neg_y[b * NC + tid] * W + neg_x[b * NC + tid]];
        out[((size_t)b * NC + tid) * C + c] = o;
    }
}

extern "C" void kernel_launch(void* const* d_in, const int* in_sizes, int n_in,
                              void* d_out, int out_size, void* d_ws, size_t ws_size,
                              hipStream_t stream) {
    (void)in_sizes; (void)n_in; (void)d_ws; (void)ws_size; (void)out_size;
    vpe_kernel<<<dim3(B * C), dim3(T), 0, stream>>>(
        (const float*)d_in[0],   // features
        (const float*)d_in[1],   // boxes
        (const int*)d_in[2],     // gt_classes
        (const int*)d_in[3],     // neg_y
        (const int*)d_in[4],     // neg_x
        (const int*)d_in[5],     // image_h
        (const int*)d_in[6],     // image_w
        (float*)d_out);
}